// Round 3
// baseline (556.568 us; speedup 1.0000x reference)
//
#include <hip/hip_runtime.h>
#include <hip/hip_bf16.h>
#include <math.h>

#define B_ 16
#define L_ 32768
#define H_ 64
#define N_ 16
#define DM_ 32
#define T_ 128
#define C_ 256   /* L_/T_ */
#define TS_ 16   /* subtile rows */
#define STR_ 68  /* LDS row stride: 4*68 % 32 == 16 -> 2-way aliasing (free) */

typedef __attribute__((ext_vector_type(8))) short short8;
typedef __attribute__((ext_vector_type(4))) float floatx4;
typedef unsigned short ushort_t;

// gelu matching jax.nn.gelu(approximate=True)
__device__ __forceinline__ float fast_gelu(float v) {
    float z = fmaf(0.044715f * v, v * v, v) * 0.7978845608028654f;
#if __has_builtin(__builtin_amdgcn_exp2f) && __has_builtin(__builtin_amdgcn_rcpf)
    float e = __builtin_amdgcn_exp2f(z * 2.8853900817779268f);
    float t = 1.0f - 2.0f * __builtin_amdgcn_rcpf(e + 1.0f);
#else
    float t = tanhf(z);
#endif
    return 0.5f * v * (1.0f + t);
}

__device__ __forceinline__ unsigned short bf16_rne(float f) {
    unsigned u = __float_as_uint(f);
    return (unsigned short)((u + 0x7FFFu + ((u >> 16) & 1u)) >> 16);
}
__device__ __forceinline__ float bf16_tof(unsigned short h) {
    return __uint_as_float(((unsigned)h) << 16);
}
// split 8 floats into bf16 hi + bf16 lo fragments (packed)
__device__ __forceinline__ void cvt8(const float* f, short8* hi, short8* lo) {
    union { unsigned u[4]; short8 s; } Hh, Ll;
    #pragma unroll
    for (int jp = 0; jp < 4; ++jp) {
        unsigned short h0 = bf16_rne(f[2*jp]), h1 = bf16_rne(f[2*jp+1]);
        Hh.u[jp] = (unsigned)h0 | ((unsigned)h1 << 16);
        float l0 = f[2*jp]   - bf16_tof(h0);
        float l1 = f[2*jp+1] - bf16_tof(h1);
        Ll.u[jp] = (unsigned)bf16_rne(l0) | ((unsigned)bf16_rne(l1) << 16);
    }
    *hi = Hh.s; *lo = Ll.s;
}

// ---------------- fused prep: film MLP | SSM coefs | W fragment table ------
// block 0: cond MLP + FiLM   block 1: coef   block 2: Wf (bf16 hi/lo frags)
__global__ void prep_kernel(const float* __restrict__ cp,
    const float* __restrict__ W0, const float* __restrict__ b0,
    const float* __restrict__ W1, const float* __restrict__ b1,
    const float* __restrict__ W2, const float* __restrict__ b2,
    const float* __restrict__ Wfilm, const float* __restrict__ bfilm,
    const float* __restrict__ W_lin,
    const float* __restrict__ log_dt,
    const float* __restrict__ A_re, const float* __restrict__ A_im,
    const float* __restrict__ C_re, const float* __restrict__ C_im,
    float* __restrict__ film, float* __restrict__ coef, ushort_t* __restrict__ gWf) {
    int tid = threadIdx.x;
    if (blockIdx.x == 0) {
        __shared__ float ca[B_][DM_];
        __shared__ float cb[B_][DM_];
        int b = tid >> 4, jj = tid & 15;
        #pragma unroll
        for (int t = 0; t < 2; ++t) {
            int j = jj + 16*t;
            float acc = fmaf(cp[b*2+0], W0[j], fmaf(cp[b*2+1], W0[DM_+j], b0[j]));
            ca[b][j] = fast_gelu(acc);
        }
        __syncthreads();
        #pragma unroll
        for (int t = 0; t < 2; ++t) {
            int j = jj + 16*t;
            float acc = b1[j];
            #pragma unroll
            for (int i = 0; i < DM_; ++i) acc = fmaf(ca[b][i], W1[i*DM_+j], acc);
            cb[b][j] = fast_gelu(acc);
        }
        __syncthreads();
        float c2[2];
        #pragma unroll
        for (int t = 0; t < 2; ++t) {
            int j = jj + 16*t;
            float acc = b2[j];
            #pragma unroll
            for (int i = 0; i < DM_; ++i) acc = fmaf(cb[b][i], W2[i*DM_+j], acc);
            c2[t] = fast_gelu(acc);
        }
        __syncthreads();
        #pragma unroll
        for (int t = 0; t < 2; ++t) ca[b][jj+16*t] = c2[t];
        __syncthreads();
        #pragma unroll
        for (int t = 0; t < 8; ++t) {
            int k = jj + 16*t;
            float a = bfilm[k];
            #pragma unroll
            for (int i = 0; i < DM_; ++i) a = fmaf(ca[b][i], Wfilm[i*2*H_+k], a);
            film[b*2*H_ + k] = a;
        }
    } else if (blockIdx.x == 1) {
        for (int it = 0; it < 4; ++it) {
            int g = tid + 256*it;
            int h = g >> 4, n = g & 15;
            float dt = expf(log_dt[h]);
            float Ar = A_re[h*N_+n], Ai = A_im[h*N_+n];
            float ar = dt*Ar, ai = dt*Ai;
            float er = expf(ar);
            float wr = er * cosf(ai), wi = er * sinf(ai);
            float eT = expf((float)T_ * ar);
            float aT = (float)T_ * ai;
            float wTr = eT * cosf(aT), wTi = eT * sinf(aT);
            float d  = Ar*Ar + Ai*Ai;
            float nr = wr - 1.0f, ni = wi;
            float qr = (nr*Ar + ni*Ai) / d;
            float qi = (ni*Ar - nr*Ai) / d;
            float Cr = C_re[h*N_+n], Ci = C_im[h*N_+n];
            float cr = 2.0f * (Cr*qr - Ci*qi);
            float ci = 2.0f * (Cr*qi + Ci*qr);
            coef[(n*6+0)*H_+h] = wr;
            coef[(n*6+1)*H_+h] = wi;
            coef[(n*6+2)*H_+h] = wTr;
            coef[(n*6+3)*H_+h] = wTi;
            coef[(n*6+4)*H_+h] = cr;
            coef[(n*6+5)*H_+h] = ci;
        }
    } else {
        int lane = tid & 63, grp = tid >> 6;
        int m = lane & 15, quad = lane >> 4;
        for (int f = grp*4; f < grp*4 + 4; ++f) {
            int t = f >> 3, kt = (f >> 2) & 1, nt = f & 3;
            float fv[8];
            #pragma unroll
            for (int j = 0; j < 8; ++j)
                fv[j] = W_lin[(kt*32 + quad*8 + j)*H_ + nt*16 + m];
            short8 hi, lo;
            cvt8(fv, &hi, &lo);
            ((short8*)gWf)[f*64 + lane] = t ? lo : hi;
        }
    }
}

// ---------------- phase 2: cross-chunk prefix combine (prefetch depth 16) --
__global__ void chunk_scan_kernel(float* __restrict__ states,
                                  const float* __restrict__ coef) {
    int t = blockIdx.x * blockDim.x + threadIdx.x;   // 16384 = B*N*H
    int h = t & 63, n = (t >> 6) & 15, b = t >> 10;
    float wTr = coef[(n*6+2)*H_+h], wTi = coef[(n*6+3)*H_+h];
    float2* sp = (float2*)states + (size_t)b*C_*N_*H_ + (size_t)n*H_ + h;
    const int stride = N_*H_;
    float car = 0.f, cai = 0.f;
    float2 buf[16];
    #pragma unroll
    for (int i = 0; i < 16; ++i) buf[i] = sp[(size_t)i*stride];
    for (int cg = 0; cg < C_; cg += 16) {
        float2 nb[16];
        #pragma unroll
        for (int i = 0; i < 16; ++i)
            nb[i] = (cg + 16 + i < C_) ? sp[(size_t)(cg+16+i)*stride]
                                       : make_float2(0.f, 0.f);
        #pragma unroll
        for (int i = 0; i < 16; ++i) {
            float2 v = buf[i];
            sp[(size_t)(cg+i)*stride] = make_float2(car, cai);
            float nr2 = fmaf(wTr, car, fmaf(-wTi, cai, v.x));
            float ni2 = fmaf(wTr, cai, fmaf( wTi, car, v.y));
            car = nr2; cai = ni2;
            buf[i] = nb[i];
        }
    }
}

// ---------------- phases 1 & 3: MFMA GEMM + diagonal scan, pipelined -------
// u ~= x_hi@W_hi + x_lo@W_hi + x_hi@W_lo  (split-bf16, err ~2^-17)
template<int PHASE>
__global__ __launch_bounds__(256, PHASE == 1 ? 4 : 3)
void gemm_scan_kernel(const float* __restrict__ x,
                      const ushort_t* __restrict__ gWf,
                      const float* __restrict__ b_lin,
                      const float* __restrict__ coef, float* __restrict__ states,
                      const float* __restrict__ D, const float* __restrict__ film,
                      float* __restrict__ out) {
    extern __shared__ char smem[];
    short8* Wf   = (short8*)smem;                         // 16 KB
    float*  uBase = (float*)(smem + 16384);
    const int tid  = threadIdx.x;
    const int lane = tid & 63;
    const int wv   = tid >> 6;
    float* myu = uBase + wv * (TS_*STR_);
    float* xt  = uBase + 4*(TS_*STR_) + wv*(TS_*STR_);    // phase 3 only

    // stage W fragment table (16 KB) global -> LDS, then one barrier
    {
        const short8* src = (const short8*)gWf;
        #pragma unroll
        for (int i = 0; i < 4; ++i) Wf[i*256 + tid] = src[i*256 + tid];
    }
    __syncthreads();

    const int q = blockIdx.x*4 + wv;        // chunk id 0..4095
    const int b = q >> 8;
    const int c = q & 255;
    const int m = lane & 15;
    const int quad = lane >> 4;

    float wr[N_], wi[N_], sr[N_], si[N_];
    float cr[N_], ci[N_];
    float g_ = 0.f, be_ = 0.f, Dh = 0.f;
    #pragma unroll
    for (int n = 0; n < N_; ++n) {
        wr[n] = coef[(n*6+0)*H_ + lane];
        wi[n] = coef[(n*6+1)*H_ + lane];
    }
    if (PHASE == 1) {
        #pragma unroll
        for (int n = 0; n < N_; ++n) { sr[n] = 0.f; si[n] = 0.f; }
    } else {
        #pragma unroll
        for (int n = 0; n < N_; ++n) {
            cr[n] = coef[(n*6+4)*H_ + lane];
            ci[n] = coef[(n*6+5)*H_ + lane];
            size_t idx = (((size_t)q*N_ + n)*H_ + lane)*2;
            sr[n] = states[idx]; si[n] = states[idx+1];
        }
        g_  = film[b*2*H_ + lane];
        be_ = film[b*2*H_ + H_ + lane];
        Dh  = D[lane];
    }
    float blv[4];
    #pragma unroll
    for (int nt = 0; nt < 4; ++nt) blv[nt] = b_lin[nt*16 + m];

    const float* xp = x + ((size_t)b*L_ + (size_t)c*T_)*H_;
    float* op = out + ((size_t)b*L_ + (size_t)c*T_)*H_;
    const float* a0 = xp + m*H_ + quad*8;   // this lane's frag source

    // prefetch subtile 0
    float4 p00 = *(const float4*)(a0);
    float4 p01 = *(const float4*)(a0 + 4);
    float4 p10 = *(const float4*)(a0 + 32);
    float4 p11 = *(const float4*)(a0 + 36);

    for (int s = 0; s < T_/TS_; ++s) {
        float4 c00 = p00, c01 = p01, c10 = p10, c11 = p11;
        if (s < T_/TS_ - 1) {
            const float* nx = a0 + (size_t)(s+1)*TS_*H_;
            p00 = *(const float4*)(nx);
            p01 = *(const float4*)(nx + 4);
            p10 = *(const float4*)(nx + 32);
            p11 = *(const float4*)(nx + 36);
        }
        if (PHASE == 3) {
            // raw-x transpose to LDS (b128 writes, bank-uniform)
            *(float4*)(xt + m*STR_ + quad*8)          = c00;
            *(float4*)(xt + m*STR_ + quad*8 + 4)      = c01;
            *(float4*)(xt + m*STR_ + 32 + quad*8)     = c10;
            *(float4*)(xt + m*STR_ + 32 + quad*8 + 4) = c11;
        }
        short8 ah[2], al[2];
        {
            float f0[8] = {c00.x,c00.y,c00.z,c00.w,c01.x,c01.y,c01.z,c01.w};
            cvt8(f0, &ah[0], &al[0]);
            float f1[8] = {c10.x,c10.y,c10.z,c10.w,c11.x,c11.y,c11.z,c11.w};
            cvt8(f1, &ah[1], &al[1]);
        }
        #pragma unroll
        for (int nt = 0; nt < 4; ++nt) {
            floatx4 acc = {0.f, 0.f, 0.f, 0.f};
            #pragma unroll
            for (int kt = 0; kt < 2; ++kt) {
                short8 bh = Wf[(kt*4 + nt)*64 + lane];
                short8 bl = Wf[((2+kt)*4 + nt)*64 + lane];
                acc = __builtin_amdgcn_mfma_f32_16x16x32_bf16(ah[kt], bh, acc, 0, 0, 0);
                acc = __builtin_amdgcn_mfma_f32_16x16x32_bf16(al[kt], bh, acc, 0, 0, 0);
                acc = __builtin_amdgcn_mfma_f32_16x16x32_bf16(ah[kt], bl, acc, 0, 0, 0);
            }
            // C layout: col = nt*16 + m, row = quad*4 + r
            #pragma unroll
            for (int r = 0; r < 4; ++r)
                myu[(quad*4 + r)*STR_ + nt*16 + m] = fast_gelu(acc[r] + blv[nt]);
        }
        // scan TS_ rows (lane = h); per-wave DS ordering covers own writes
        for (int l = 0; l < TS_; ++l) {
            float uv = myu[l*STR_ + lane];
            if (PHASE == 1) {
                #pragma unroll
                for (int n = 0; n < N_; ++n) {
                    float nr = fmaf(wr[n], sr[n], fmaf(-wi[n], si[n], uv));
                    float ni = fmaf(wr[n], si[n], wi[n]*sr[n]);
                    sr[n] = nr; si[n] = ni;
                }
            } else {
                float xg = xt[l*STR_ + lane];
                float y0 = 0.f, y1 = 0.f;
                #pragma unroll
                for (int n = 0; n < N_; ++n) {
                    float nr = fmaf(wr[n], sr[n], fmaf(-wi[n], si[n], uv));
                    float ni = fmaf(wr[n], si[n], wi[n]*sr[n]);
                    sr[n] = nr; si[n] = ni;
                    y0 = fmaf(cr[n], nr, y0);
                    y1 = fmaf(ci[n], ni, y1);
                }
                float y  = fmaf(Dh, uv, y0 - y1);        // conv + D*u
                float yg = fast_gelu(fmaf(y, g_, be_));  // FiLM + gelu
                op[(s*TS_ + l)*H_ + lane] = xg * yg;     // side-chain gate
            }
        }
    }
    if (PHASE == 1) {
        #pragma unroll
        for (int n = 0; n < N_; ++n) {
            size_t idx = (((size_t)q*N_ + n)*H_ + lane)*2;
            states[idx]   = sr[n];
            states[idx+1] = si[n];
        }
    }
}

extern "C" void kernel_launch(void* const* d_in, const int* in_sizes, int n_in,
                              void* d_out, int out_size, void* d_ws, size_t ws_size,
                              hipStream_t stream) {
    const float* x     = (const float*)d_in[0];
    const float* cp    = (const float*)d_in[1];
    const float* W0    = (const float*)d_in[2];
    const float* b0    = (const float*)d_in[3];
    const float* W1    = (const float*)d_in[4];
    const float* b1    = (const float*)d_in[5];
    const float* W2    = (const float*)d_in[6];
    const float* b2    = (const float*)d_in[7];
    const float* W_lin = (const float*)d_in[8];
    const float* b_lin = (const float*)d_in[9];
    const float* log_dt= (const float*)d_in[10];
    const float* A_re  = (const float*)d_in[11];
    const float* A_im  = (const float*)d_in[12];
    const float* C_re  = (const float*)d_in[13];
    const float* C_im  = (const float*)d_in[14];
    const float* D     = (const float*)d_in[15];
    const float* W_f   = (const float*)d_in[16];
    const float* b_f   = (const float*)d_in[17];
    float* out = (float*)d_out;

    float*    film   = (float*)d_ws;                // 2048 floats
    float*    coef   = film + B_*2*H_;              // 6144 floats
    ushort_t* gWf    = (ushort_t*)(coef + 6*H_*N_); // 8192 ushorts (16 KB)
    float*    states = (float*)(gWf + 16*64*8);     // B*C*N*H*2 = 8.4M floats

    prep_kernel<<<3, 256, 0, stream>>>(cp, W0, b0, W1, b1, W2, b2, W_f, b_f,
                                       W_lin, log_dt, A_re, A_im, C_re, C_im,
                                       film, coef, gWf);
    gemm_scan_kernel<1><<<(B_*C_)/4, 256, 16384 + 4*TS_*STR_*4, stream>>>(
        x, gWf, b_lin, coef, states, nullptr, nullptr, nullptr);
    chunk_scan_kernel<<<(B_*N_*H_)/256, 256, 0, stream>>>(states, coef);
    gemm_scan_kernel<3><<<(B_*C_)/4, 256, 16384 + 8*TS_*STR_*4, stream>>>(
        x, gWf, b_lin, coef, states, D, film, out);
}